// Round 1
// baseline (486.148 us; speedup 1.0000x reference)
//
#include <hip/hip_runtime.h>
#include <math.h>

#define BB 4
#define DL 150
#define PL 1000
#define CD 64
#define NC1 40
#define NC2 80
#define NC3 160
#define L1O 997
#define L2O 990
#define L3O 979

__device__ __forceinline__ float relu_(float x){ return fmaxf(x, 0.f); }
__device__ __forceinline__ float lrelu_(float x){ return x > 0.f ? x : 0.01f * x; }

// monotonic float<->uint encoding for atomic max
__device__ __forceinline__ unsigned fenc(float x){
  unsigned u = __float_as_uint(x);
  return (u & 0x80000000u) ? ~u : (u | 0x80000000u);
}
__device__ __forceinline__ float fdec(unsigned u){
  return __uint_as_float((u & 0x80000000u) ? (u & 0x7fffffffu) : ~u);
}

// ---- conv1: embed lookup + conv(64->40, K=4) + relu ----
__global__ void k_conv1(const int* __restrict__ prot, const float* __restrict__ emb,
                        const float* __restrict__ w, const float* __restrict__ bias,
                        float* __restrict__ out){
  int idx = blockIdx.x * 256 + threadIdx.x;
  const int total = BB * NC1 * L1O;
  if (idx >= total) return;
  int p = idx % L1O; int t = idx / L1O; int co = t % NC1; int b = t / NC1;
  float acc = bias[co];
  const float* wr = w + co * (CD * 4);
  const int* pr = prot + b * PL + p;
  for (int k = 0; k < 4; k++){
    const float* e = emb + pr[k] * CD;
    #pragma unroll 16
    for (int ci = 0; ci < CD; ci++) acc += e[ci] * wr[ci * 4 + k];
  }
  out[idx] = relu_(acc);
}

// ---- conv2: 40->80, K=8 ----
__global__ void k_conv2(const float* __restrict__ x, const float* __restrict__ w,
                        const float* __restrict__ bias, float* __restrict__ out){
  int idx = blockIdx.x * 256 + threadIdx.x;
  const int total = BB * NC2 * L2O;
  if (idx >= total) return;
  int p = idx % L2O; int t = idx / L2O; int co = t % NC2; int b = t / NC2;
  float acc = bias[co];
  const float* xr = x + b * NC1 * L1O + p;
  const float* wr = w + co * (NC1 * 8);
  for (int ci = 0; ci < NC1; ci++){
    #pragma unroll
    for (int k = 0; k < 8; k++) acc += xr[ci * L1O + k] * wr[ci * 8 + k];
  }
  out[idx] = relu_(acc);
}

// ---- conv3: 80->160, K=12 ----
__global__ void k_conv3(const float* __restrict__ x, const float* __restrict__ w,
                        const float* __restrict__ bias, float* __restrict__ out){
  int idx = blockIdx.x * 256 + threadIdx.x;
  const int total = BB * NC3 * L3O;
  if (idx >= total) return;
  int p = idx % L3O; int t = idx / L3O; int co = t % NC3; int b = t / NC3;
  float acc = bias[co];
  const float* xr = x + b * NC2 * L2O + p;
  const float* wr = w + co * (NC2 * 12);
  for (int ci = 0; ci < NC2; ci++){
    #pragma unroll
    for (int k = 0; k < 12; k++) acc += xr[ci * L2O + k] * wr[ci * 12 + k];
  }
  out[idx] = relu_(acc);
}

// ---- drug attention: drug @ Wd.T + bd, masked by num_atoms ----
__global__ void k_datt(const float* __restrict__ drug, const int* __restrict__ natoms,
                       const float* __restrict__ Wd, const float* __restrict__ bd,
                       float* __restrict__ out){
  int idx = blockIdx.x * 256 + threadIdx.x;
  const int total = BB * DL * NC3;
  if (idx >= total) return;
  int c = idx % NC3; int t = idx / NC3; int i = t % DL; int b = t / DL;
  float acc = bd[c];
  const float* x = drug + (b * DL + i) * NC3;
  const float* w = Wd + c * NC3;
  #pragma unroll 8
  for (int k = 0; k < NC3; k++) acc += x[k] * w[k];
  out[idx] = (i < natoms[b]) ? acc : 0.f;
}

// ---- protein attention: pconv^T @ Wp.T + bp, masked by token>0 ----
__global__ void k_patt(const float* __restrict__ pconv, const int* __restrict__ prot,
                       const float* __restrict__ Wp, const float* __restrict__ bp,
                       float* __restrict__ out){
  int idx = blockIdx.x * 256 + threadIdx.x;
  const int total = BB * L3O * NC3;
  if (idx >= total) return;
  int c = idx % NC3; int t = idx / NC3; int j = t % L3O; int b = t / L3O;
  float acc = bp[c];
  const float* x = pconv + b * NC3 * L3O + j;
  const float* w = Wp + c * NC3;
  #pragma unroll 8
  for (int k = 0; k < NC3; k++) acc += x[k * L3O] * w[k];
  out[idx] = (prot[b * PL + j] > 0) ? acc : 0.f;
}

// ---- means of relu(da_i + pa_j) over j (Cmean) and over i (Pmean) ----
// one block per (b, c); 256 threads
__global__ void k_means(const float* __restrict__ datt, const float* __restrict__ patt,
                        float* __restrict__ cmean, float* __restrict__ pmean){
  __shared__ float sda[DL];
  __shared__ float spa[L3O];
  int b = blockIdx.x / NC3, c = blockIdx.x % NC3;
  int tid = threadIdx.x;
  for (int i = tid; i < DL; i += 256) sda[i] = datt[(b * DL + i) * NC3 + c];
  for (int j = tid; j < L3O; j += 256) spa[j] = patt[(b * L3O + j) * NC3 + c];
  __syncthreads();
  if (tid < DL){
    float v = sda[tid], a = 0.f;
    for (int j = 0; j < L3O; j++) a += relu_(v + spa[j]);
    cmean[(b * DL + tid) * NC3 + c] = a * (1.f / L3O);
  }
  for (int j = tid; j < L3O; j += 256){
    float v = spa[j], a = 0.f;
    for (int i = 0; i < DL; i++) a += relu_(v + sda[i]);
    pmean[(b * L3O + j) * NC3 + c] = a * (1.f / DL);
  }
}

// ---- drug gate: sigmoid(Cmean @ Watt.T + batt); modulate drug; atomic max-pool ----
// one block per (b, i); 160 threads
__global__ void k_atteD(const float* __restrict__ cmean, const float* __restrict__ Watt,
                        const float* __restrict__ batt, const float* __restrict__ drug,
                        unsigned* __restrict__ denc){
  int b = blockIdx.x / DL, i = blockIdx.x % DL;
  int c = threadIdx.x;
  __shared__ float sm[NC3];
  sm[c] = cmean[(b * DL + i) * NC3 + c];
  __syncthreads();
  float acc = batt[c];
  const float* w = Watt + c * NC3;
  #pragma unroll 8
  for (int k = 0; k < NC3; k++) acc += sm[k] * w[k];
  float atte = 1.f / (1.f + expf(-acc));
  float m = drug[(b * DL + i) * NC3 + c] * (0.5f + atte);
  atomicMax(&denc[b * NC3 + c], fenc(m));
}

// ---- protein gate ----
// one block per (b, j); 160 threads
__global__ void k_atteP(const float* __restrict__ pmean, const float* __restrict__ Watt,
                        const float* __restrict__ batt, const float* __restrict__ pconv,
                        unsigned* __restrict__ penc){
  int b = blockIdx.x / L3O, j = blockIdx.x % L3O;
  int c = threadIdx.x;
  __shared__ float sm[NC3];
  sm[c] = pmean[(b * L3O + j) * NC3 + c];
  __syncthreads();
  float acc = batt[c];
  const float* w = Watt + c * NC3;
  #pragma unroll 8
  for (int k = 0; k < NC3; k++) acc += sm[k] * w[k];
  float atte = 1.f / (1.f + expf(-acc));
  float m = pconv[(b * NC3 + c) * L3O + j] * (0.5f + atte);
  atomicMax(&penc[b * NC3 + c], fenc(m));
}

// ---- MLP layer 1: 320 -> 1024 ----
__global__ void k_mlp1(const unsigned* __restrict__ denc, const unsigned* __restrict__ penc,
                       const float* __restrict__ W1, const float* __restrict__ bf1,
                       float* __restrict__ f1){
  int b = blockIdx.x >> 2;
  int t = ((blockIdx.x & 3) << 8) + threadIdx.x;
  __shared__ float sp[2 * NC3];
  for (int k = threadIdx.x; k < NC3; k += 256) sp[k] = fdec(denc[b * NC3 + k]);
  for (int k = threadIdx.x; k < NC3; k += 256) sp[NC3 + k] = fdec(penc[b * NC3 + k]);
  __syncthreads();
  float acc = bf1[t];
  const float* w = W1 + t * 320;
  #pragma unroll 8
  for (int k = 0; k < 320; k++) acc += sp[k] * w[k];
  f1[b * 1024 + t] = lrelu_(acc);
}

// ---- MLP layer 2: 1024 -> 1024 ----
__global__ void k_mlp2(const float* __restrict__ f1, const float* __restrict__ W2,
                       const float* __restrict__ bf2, float* __restrict__ f2){
  int b = blockIdx.x >> 2;
  int t = ((blockIdx.x & 3) << 8) + threadIdx.x;
  __shared__ float s[1024];
  for (int k = threadIdx.x; k < 1024; k += 256) s[k] = f1[b * 1024 + k];
  __syncthreads();
  float acc = bf2[t];
  const float* w = W2 + t * 1024;
  #pragma unroll 8
  for (int k = 0; k < 1024; k++) acc += s[k] * w[k];
  f2[b * 1024 + t] = lrelu_(acc);
}

// ---- MLP layer 3: 1024 -> 512 ----
__global__ void k_mlp3(const float* __restrict__ f2, const float* __restrict__ W3,
                       const float* __restrict__ bf3, float* __restrict__ f3){
  int b = blockIdx.x >> 1;
  int t = ((blockIdx.x & 1) << 8) + threadIdx.x;
  __shared__ float s[1024];
  for (int k = threadIdx.x; k < 1024; k += 256) s[k] = f2[b * 1024 + k];
  __syncthreads();
  float acc = bf3[t];
  const float* w = W3 + t * 1024;
  #pragma unroll 8
  for (int k = 0; k < 1024; k++) acc += s[k] * w[k];
  f3[b * 512 + t] = lrelu_(acc);
}

// ---- MLP out: 512 -> 2 ---- one block of 256: 8 groups of 32 lanes
__global__ void k_mlp4(const float* __restrict__ f3, const float* __restrict__ Wo,
                       const float* __restrict__ bo, float* __restrict__ out){
  int tid = threadIdx.x;
  int g = tid >> 5;          // 0..7 -> (b, o)
  int lane = tid & 31;
  int b = g >> 1, o = g & 1;
  float acc = 0.f;
  for (int k = lane; k < 512; k += 32) acc += f3[b * 512 + k] * Wo[o * 512 + k];
  for (int off = 16; off; off >>= 1) acc += __shfl_down(acc, off, 32);
  if (lane == 0) out[b * 2 + o] = acc + bo[o];
}

extern "C" void kernel_launch(void* const* d_in, const int* in_sizes, int n_in,
                              void* d_out, int out_size, void* d_ws, size_t ws_size,
                              hipStream_t stream) {
  const float* drug  = (const float*)d_in[0];
  const int*   natoms= (const int*)d_in[1];
  const int*   prot  = (const int*)d_in[2];
  const float* emb   = (const float*)d_in[3];
  const float* w1    = (const float*)d_in[4];
  const float* b1    = (const float*)d_in[5];
  const float* w2    = (const float*)d_in[6];
  const float* b2    = (const float*)d_in[7];
  const float* w3    = (const float*)d_in[8];
  const float* b3    = (const float*)d_in[9];
  const float* Wd    = (const float*)d_in[10];
  const float* bd    = (const float*)d_in[11];
  const float* Wp    = (const float*)d_in[12];
  const float* bp    = (const float*)d_in[13];
  const float* Watt  = (const float*)d_in[14];
  const float* batt  = (const float*)d_in[15];
  const float* W1    = (const float*)d_in[16];
  const float* bf1   = (const float*)d_in[17];
  const float* W2    = (const float*)d_in[18];
  const float* bf2   = (const float*)d_in[19];
  const float* W3    = (const float*)d_in[20];
  const float* bf3   = (const float*)d_in[21];
  const float* Wo    = (const float*)d_in[22];
  const float* bo    = (const float*)d_in[23];
  float* out = (float*)d_out;

  float* ws = (float*)d_ws;
  size_t off = 0;
  float* h1    = ws + off; off += (size_t)BB * NC1 * L1O;   // 159520
  float* h2    = ws + off; off += (size_t)BB * NC2 * L2O;   // 316800
  float* pconv = ws + off; off += (size_t)BB * NC3 * L3O;   // 626560
  float* datt  = ws + off; off += (size_t)BB * DL * NC3;    // 96000
  float* patt  = ws + off; off += (size_t)BB * L3O * NC3;   // 626560
  float* cmean = ws + off; off += (size_t)BB * DL * NC3;    // 96000
  float* pmean = ws + off; off += (size_t)BB * L3O * NC3;   // 626560
  unsigned* denc = (unsigned*)(ws + off); off += BB * NC3;  // 640
  unsigned* penc = (unsigned*)(ws + off); off += BB * NC3;  // 640
  float* f1    = ws + off; off += BB * 1024;
  float* f2    = ws + off; off += BB * 1024;
  float* f3    = ws + off; off += BB * 512;

  // reset atomic max-pool accumulators (encoded domain: 0 == -inf)
  hipMemsetAsync(denc, 0, 2 * BB * NC3 * sizeof(unsigned), stream);

  k_conv1<<<(BB * NC1 * L1O + 255) / 256, 256, 0, stream>>>(prot, emb, w1, b1, h1);
  k_conv2<<<(BB * NC2 * L2O + 255) / 256, 256, 0, stream>>>(h1, w2, b2, h2);
  k_conv3<<<(BB * NC3 * L3O + 255) / 256, 256, 0, stream>>>(h2, w3, b3, pconv);
  k_datt <<<(BB * DL * NC3 + 255) / 256, 256, 0, stream>>>(drug, natoms, Wd, bd, datt);
  k_patt <<<(BB * L3O * NC3 + 255) / 256, 256, 0, stream>>>(pconv, prot, Wp, bp, patt);
  k_means<<<BB * NC3, 256, 0, stream>>>(datt, patt, cmean, pmean);
  k_atteD<<<BB * DL, 160, 0, stream>>>(cmean, Watt, batt, drug, denc);
  k_atteP<<<BB * L3O, 160, 0, stream>>>(pmean, Watt, batt, pconv, penc);
  k_mlp1<<<16, 256, 0, stream>>>(denc, penc, W1, bf1, f1);
  k_mlp2<<<16, 256, 0, stream>>>(f1, W2, bf2, f2);
  k_mlp3<<<8, 256, 0, stream>>>(f2, W3, bf3, f3);
  k_mlp4<<<1, 256, 0, stream>>>(f3, Wo, bo, out);
}

// Round 2
// 214.912 us; speedup vs baseline: 2.2621x; 2.2621x over previous
//
#include <hip/hip_runtime.h>
#include <math.h>

#define BB 4
#define DL 150
#define PL 1000
#define CD 64
#define NC1 40
#define NC2 80
#define NC3 160
#define L1O 997
#define L2O 990
#define L3O 979
#define L1P 1000
#define L2P 992
#define L3P 980
#define DLP 152
#define PLP 984
#define NINF (-1e30f)

__device__ __forceinline__ float relu_(float x){ return fmaxf(x, 0.f); }
__device__ __forceinline__ float lrelu_(float x){ return x > 0.f ? x : 0.01f * x; }

__device__ __forceinline__ unsigned fenc(float x){
  unsigned u = __float_as_uint(x);
  return (u & 0x80000000u) ? ~u : (u | 0x80000000u);
}
__device__ __forceinline__ float fdec(unsigned u){
  return __uint_as_float((u & 0x80000000u) ? (u & 0x7fffffffu) : ~u);
}

// ---- proj table: proj[tok][k][co] = sum_ci emb[tok][ci] * w1[co][ci][k] ----
__global__ void k_proj(const float* __restrict__ emb, const float* __restrict__ w1,
                       float* __restrict__ projG){
  int e = blockIdx.x * 256 + threadIdx.x;
  if (e >= 26 * 160) return;
  int tok = e / 160, rem = e % 160, k = rem / 40, co = rem % 40;
  float a = 0.f;
  const float* er = emb + tok * CD;
  const float* wr = w1 + co * (CD * 4) + k;
  #pragma unroll 8
  for (int ci = 0; ci < CD; ci++) a = fmaf(er[ci], wr[ci * 4], a);
  projG[tok * 161 + k * 40 + co] = a;
}

// ---- conv1 apply: h1[b][co][p] = relu(b1[co] + sum_k proj[tok[p+k]][k][co]) ----
__global__ __launch_bounds__(256) void k_conv1(const int* __restrict__ prot,
                        const float* __restrict__ projG, const float* __restrict__ b1,
                        float* __restrict__ h1){
  __shared__ float sp[26 * 161];
  int b = blockIdx.x / 80;
  int t = (blockIdx.x % 80) * 256 + threadIdx.x;   // 20480 per b
  for (int k = threadIdx.x; k < 26 * 161; k += 256) sp[k] = projG[k];
  __syncthreads();
  int p = t & 1023, co2 = t >> 10;                 // co2: 0..19
  if (p >= L1O) return;
  const int* pr = prot + b * PL + p;
  int t0 = pr[0], t1 = pr[1], t2 = pr[2], t3 = pr[3];
  #pragma unroll
  for (int c = 0; c < 2; c++){
    int co = co2 * 2 + c;
    float a = b1[co] + sp[t0 * 161 + co] + sp[t1 * 161 + 40 + co]
            + sp[t2 * 161 + 80 + co] + sp[t3 * 161 + 120 + co];
    h1[(size_t)(b * NC1 + co) * L1P + p] = relu_(a);
  }
}

// ---- conv2: 40->80, K=8, block=(b,co), thread=4 consecutive positions ----
__global__ __launch_bounds__(256) void k_conv2(const float* __restrict__ x,
                        const float* __restrict__ w, const float* __restrict__ bias,
                        float* __restrict__ y){
  int b = blockIdx.x / NC2, co = blockIdx.x % NC2;
  __shared__ float ws[NC1 * 8];
  for (int k = threadIdx.x; k < NC1 * 8; k += 256) ws[k] = w[co * (NC1 * 8) + k];
  __syncthreads();
  int p0 = threadIdx.x * 4;
  if (p0 >= L2O) return;
  float bv = bias[co];
  float a0 = bv, a1 = bv, a2 = bv, a3 = bv;
  const float* xb = x + (size_t)b * NC1 * L1P;
  #pragma unroll 2
  for (int ci = 0; ci < NC1; ci++){
    const float4* xr = (const float4*)(xb + ci * L1P + p0);
    float4 v0 = xr[0], v1 = xr[1], v2 = xr[2];
    float xv[12] = {v0.x,v0.y,v0.z,v0.w, v1.x,v1.y,v1.z,v1.w, v2.x,v2.y,v2.z,v2.w};
    #pragma unroll
    for (int k = 0; k < 8; k++){
      float wv = ws[ci * 8 + k];
      a0 = fmaf(xv[k],     wv, a0);
      a1 = fmaf(xv[k + 1], wv, a1);
      a2 = fmaf(xv[k + 2], wv, a2);
      a3 = fmaf(xv[k + 3], wv, a3);
    }
  }
  float* yr = y + (size_t)(b * NC2 + co) * L2P + p0;
  if (p0 + 3 < L2O){
    float4 o; o.x = relu_(a0); o.y = relu_(a1); o.z = relu_(a2); o.w = relu_(a3);
    *(float4*)yr = o;
  } else {
    float aa[4] = {a0, a1, a2, a3};
    for (int j = 0; j < 4; j++) if (p0 + j < L2O) yr[j] = relu_(aa[j]);
  }
}

// ---- conv3: 80->160, K=12 ----
__global__ __launch_bounds__(256) void k_conv3(const float* __restrict__ x,
                        const float* __restrict__ w, const float* __restrict__ bias,
                        float* __restrict__ y){
  int b = blockIdx.x / NC3, co = blockIdx.x % NC3;
  __shared__ float ws[NC2 * 12];
  for (int k = threadIdx.x; k < NC2 * 12; k += 256) ws[k] = w[co * (NC2 * 12) + k];
  __syncthreads();
  int p0 = threadIdx.x * 4;
  if (p0 >= L3O) return;
  float bv = bias[co];
  float a0 = bv, a1 = bv, a2 = bv, a3 = bv;
  const float* xb = x + (size_t)b * NC2 * L2P;
  #pragma unroll 2
  for (int ci = 0; ci < NC2; ci++){
    const float4* xr = (const float4*)(xb + ci * L2P + p0);
    float4 v0 = xr[0], v1 = xr[1], v2 = xr[2], v3 = xr[3];
    float xv[16] = {v0.x,v0.y,v0.z,v0.w, v1.x,v1.y,v1.z,v1.w,
                    v2.x,v2.y,v2.z,v2.w, v3.x,v3.y,v3.z,v3.w};
    #pragma unroll
    for (int k = 0; k < 12; k++){
      float wv = ws[ci * 12 + k];
      a0 = fmaf(xv[k],     wv, a0);
      a1 = fmaf(xv[k + 1], wv, a1);
      a2 = fmaf(xv[k + 2], wv, a2);
      a3 = fmaf(xv[k + 3], wv, a3);
    }
  }
  float* yr = y + (size_t)(b * NC3 + co) * L3P + p0;
  if (p0 + 3 < L3O){
    float4 o; o.x = relu_(a0); o.y = relu_(a1); o.z = relu_(a2); o.w = relu_(a3);
    *(float4*)yr = o;
  } else {
    float aa[4] = {a0, a1, a2, a3};
    for (int j = 0; j < 4; j++) if (p0 + j < L3O) yr[j] = relu_(aa[j]);
  }
}

// ---- fused drug-att + protein-att (+ enc init) ----
// blocks 0..79: datt (b = blk/20, c0 = (blk%20)*8), thread = i
// blocks 80..399: patt, thread = j
__global__ __launch_bounds__(256) void k_dpatt(const float* __restrict__ drug,
                        const int* __restrict__ natoms, const int* __restrict__ prot,
                        const float* __restrict__ pconv,
                        const float* __restrict__ Wd, const float* __restrict__ bd,
                        const float* __restrict__ Wp, const float* __restrict__ bp,
                        float* __restrict__ dattT, float* __restrict__ pattT,
                        unsigned* __restrict__ enc){
  int blk = blockIdx.x;
  if (blk == 0){
    for (int k = threadIdx.x; k < 2 * BB * NC3; k += 256) enc[k] = 0u;
  }
  if (blk < 80){
    int b = blk / 20, c0 = (blk % 20) * 8;
    int i = threadIdx.x;
    if (i >= DL) return;
    const float4* xr = (const float4*)(drug + ((size_t)b * DL + i) * NC3);
    float4 a[8];
    #pragma unroll
    for (int cc = 0; cc < 8; cc++) a[cc] = make_float4(0.f, 0.f, 0.f, 0.f);
    for (int k4 = 0; k4 < 40; k4++){
      float4 xv = xr[k4];
      #pragma unroll
      for (int cc = 0; cc < 8; cc++){
        float4 wv = ((const float4*)(Wd + (size_t)(c0 + cc) * NC3))[k4];
        a[cc].x = fmaf(xv.x, wv.x, a[cc].x);
        a[cc].y = fmaf(xv.y, wv.y, a[cc].y);
        a[cc].z = fmaf(xv.z, wv.z, a[cc].z);
        a[cc].w = fmaf(xv.w, wv.w, a[cc].w);
      }
    }
    bool act = i < natoms[b];
    #pragma unroll
    for (int cc = 0; cc < 8; cc++){
      float r = act ? (a[cc].x + a[cc].y + a[cc].z + a[cc].w + bd[c0 + cc]) : 0.f;
      dattT[(size_t)(b * NC3 + c0 + cc) * DLP + i] = r;
    }
  } else {
    int t = blk - 80;
    int b = t / 80, r = t % 80, jt = r / 20, c0 = (r % 20) * 8;
    int j = jt * 256 + threadIdx.x;
    if (j >= L3O) return;
    float acc[8];
    #pragma unroll
    for (int cc = 0; cc < 8; cc++) acc[cc] = bp[c0 + cc];
    const float* xc = pconv + (size_t)b * NC3 * L3P + j;
    #pragma unroll 4
    for (int ci = 0; ci < NC3; ci++){
      float xv = xc[ci * L3P];
      #pragma unroll
      for (int cc = 0; cc < 8; cc++)
        acc[cc] = fmaf(xv, Wp[(size_t)(c0 + cc) * NC3 + ci], acc[cc]);
    }
    bool act = prot[b * PL + j] > 0;
    #pragma unroll
    for (int cc = 0; cc < 8; cc++)
      pattT[(size_t)(b * NC3 + c0 + cc) * PLP + j] = act ? acc[cc] : 0.f;
  }
}

// ---- means of relu(da_i + pa_j): block=(b,c) ----
__global__ __launch_bounds__(256) void k_means(const float* __restrict__ dattT,
                        const float* __restrict__ pattT,
                        float* __restrict__ cmeanT, float* __restrict__ pmeanT){
  __shared__ float sda[DL];
  __shared__ float spa[L3O];
  int b = blockIdx.x / NC3, c = blockIdx.x % NC3;
  int tid = threadIdx.x;
  const float* dr = dattT + (size_t)(b * NC3 + c) * DLP;
  const float* pr = pattT + (size_t)(b * NC3 + c) * PLP;
  if (tid < DL) sda[tid] = dr[tid];
  for (int j = tid; j < L3O; j += 256) spa[j] = pr[j];
  __syncthreads();
  if (tid < DL){
    float v = sda[tid], a0 = 0.f, a1 = 0.f;
    int j = 0;
    for (; j + 1 < L3O; j += 2){
      a0 += relu_(v + spa[j]);
      a1 += relu_(v + spa[j + 1]);
    }
    if (j < L3O) a0 += relu_(v + spa[j]);
    cmeanT[(size_t)(b * NC3 + c) * DLP + tid] = (a0 + a1) * (1.f / L3O);
  }
  for (int j = tid; j < L3O; j += 256){
    float v = spa[j], a0 = 0.f, a1 = 0.f;
    for (int i = 0; i < DL; i += 2){
      a0 += relu_(v + sda[i]);
      a1 += relu_(v + sda[i + 1]);
    }
    pmeanT[(size_t)(b * NC3 + c) * PLP + j] = (a0 + a1) * (1.f / DL);
  }
}

// ---- fused gates: sigmoid(mean @ Watt.T + batt), modulate, block-reduce max, atomicMax ----
__global__ __launch_bounds__(256) void k_atte(const float* __restrict__ cmeanT,
                        const float* __restrict__ pmeanT, const float* __restrict__ Watt,
                        const float* __restrict__ batt, const float* __restrict__ drug,
                        const float* __restrict__ pconv, unsigned* __restrict__ enc){
  __shared__ float sred[4][8];
  int blk = blockIdx.x;
  float m[8];
  #pragma unroll
  for (int cc = 0; cc < 8; cc++) m[cc] = NINF;
  int encbase;
  if (blk < 80){
    int b = blk / 20, c0 = (blk % 20) * 8;
    encbase = b * NC3 + c0;
    int i = threadIdx.x;
    if (i < DL){
      float acc[8];
      #pragma unroll
      for (int cc = 0; cc < 8; cc++) acc[cc] = batt[c0 + cc];
      const float* xc = cmeanT + (size_t)b * NC3 * DLP + i;
      #pragma unroll 4
      for (int k = 0; k < NC3; k++){
        float xv = xc[(size_t)k * DLP];
        #pragma unroll
        for (int cc = 0; cc < 8; cc++)
          acc[cc] = fmaf(xv, Watt[(size_t)(c0 + cc) * NC3 + k], acc[cc]);
      }
      const float* gr = drug + ((size_t)b * DL + i) * NC3 + c0;
      #pragma unroll
      for (int cc = 0; cc < 8; cc++){
        float atte = 1.f / (1.f + expf(-acc[cc]));
        m[cc] = gr[cc] * (0.5f + atte);
      }
    }
  } else {
    int t = blk - 80;
    int b = t / 80, r = t % 80, jt = r / 20, c0 = (r % 20) * 8;
    encbase = 2 * BB * NC3 / 2 + b * NC3 + c0;   // 640 + ...
    int j = jt * 256 + threadIdx.x;
    if (j < L3O){
      float acc[8];
      #pragma unroll
      for (int cc = 0; cc < 8; cc++) acc[cc] = batt[c0 + cc];
      const float* xc = pmeanT + (size_t)b * NC3 * PLP + j;
      #pragma unroll 4
      for (int k = 0; k < NC3; k++){
        float xv = xc[(size_t)k * PLP];
        #pragma unroll
        for (int cc = 0; cc < 8; cc++)
          acc[cc] = fmaf(xv, Watt[(size_t)(c0 + cc) * NC3 + k], acc[cc]);
      }
      const float* gr = pconv + (size_t)b * NC3 * L3P + j;
      #pragma unroll
      for (int cc = 0; cc < 8; cc++){
        float atte = 1.f / (1.f + expf(-acc[cc]));
        m[cc] = gr[(size_t)(c0 + cc) * L3P] * (0.5f + atte);
      }
    }
  }
  int wave = threadIdx.x >> 6, lane = threadIdx.x & 63;
  #pragma unroll
  for (int cc = 0; cc < 8; cc++){
    float v = m[cc];
    for (int off = 1; off < 64; off <<= 1) v = fmaxf(v, __shfl_xor(v, off, 64));
    if (lane == 0) sred[wave][cc] = v;
  }
  __syncthreads();
  if (threadIdx.x < 8){
    float v = fmaxf(fmaxf(sred[0][threadIdx.x], sred[1][threadIdx.x]),
                    fmaxf(sred[2][threadIdx.x], sred[3][threadIdx.x]));
    atomicMax(&enc[encbase + threadIdx.x], fenc(v));
  }
}

// ---- MLP 1: 320 -> 1024, 4-way K-split ----
__global__ __launch_bounds__(256) void k_mlp1(const unsigned* __restrict__ enc,
                        const float* __restrict__ W1, const float* __restrict__ bf1,
                        float* __restrict__ f1){
  int b = blockIdx.x >> 4;
  int o = (blockIdx.x & 15) * 64 + (threadIdx.x >> 2);
  int q = threadIdx.x & 3;
  int k0 = q * 80;
  const float4* wr = (const float4*)(W1 + (size_t)o * 320 + k0);
  float4 a = make_float4(0.f, 0.f, 0.f, 0.f);
  for (int mI = 0; mI < 20; mI++){
    float4 wv = wr[mI];
    int k = k0 + mI * 4;
    const unsigned* e = (k < 160) ? (enc + b * NC3 + k) : (enc + 2 * BB * NC3 / 2 + b * NC3 + (k - 160));
    a.x = fmaf(fdec(e[0]), wv.x, a.x);
    a.y = fmaf(fdec(e[1]), wv.y, a.y);
    a.z = fmaf(fdec(e[2]), wv.z, a.z);
    a.w = fmaf(fdec(e[3]), wv.w, a.w);
  }
  float r = a.x + a.y + a.z + a.w;
  r += __shfl_xor(r, 1, 64);
  r += __shfl_xor(r, 2, 64);
  if (q == 0) f1[b * 1024 + o] = lrelu_(r + bf1[o]);
}

// ---- MLP 2: 1024 -> 1024 ----
__global__ __launch_bounds__(256) void k_mlp2(const float* __restrict__ x,
                        const float* __restrict__ W, const float* __restrict__ bias,
                        float* __restrict__ y){
  int b = blockIdx.x >> 4;
  int o = (blockIdx.x & 15) * 64 + (threadIdx.x >> 2);
  int q = threadIdx.x & 3;
  int k0 = q * 256;
  const float4* wr = (const float4*)(W + (size_t)o * 1024 + k0);
  const float4* xr = (const float4*)(x + b * 1024 + k0);
  float4 a = make_float4(0.f, 0.f, 0.f, 0.f);
  #pragma unroll 4
  for (int mI = 0; mI < 64; mI++){
    float4 wv = wr[mI], xv = xr[mI];
    a.x = fmaf(xv.x, wv.x, a.x);
    a.y = fmaf(xv.y, wv.y, a.y);
    a.z = fmaf(xv.z, wv.z, a.z);
    a.w = fmaf(xv.w, wv.w, a.w);
  }
  float r = a.x + a.y + a.z + a.w;
  r += __shfl_xor(r, 1, 64);
  r += __shfl_xor(r, 2, 64);
  if (q == 0) y[b * 1024 + o] = lrelu_(r + bias[o]);
}

// ---- MLP 3: 1024 -> 512 ----
__global__ __launch_bounds__(256) void k_mlp3(const float* __restrict__ x,
                        const float* __restrict__ W, const float* __restrict__ bias,
                        float* __restrict__ y){
  int b = blockIdx.x >> 3;
  int o = (blockIdx.x & 7) * 64 + (threadIdx.x >> 2);
  int q = threadIdx.x & 3;
  int k0 = q * 256;
  const float4* wr = (const float4*)(W + (size_t)o * 1024 + k0);
  const float4* xr = (const float4*)(x + b * 1024 + k0);
  float4 a = make_float4(0.f, 0.f, 0.f, 0.f);
  #pragma unroll 4
  for (int mI = 0; mI < 64; mI++){
    float4 wv = wr[mI], xv = xr[mI];
    a.x = fmaf(xv.x, wv.x, a.x);
    a.y = fmaf(xv.y, wv.y, a.y);
    a.z = fmaf(xv.z, wv.z, a.z);
    a.w = fmaf(xv.w, wv.w, a.w);
  }
  float r = a.x + a.y + a.z + a.w;
  r += __shfl_xor(r, 1, 64);
  r += __shfl_xor(r, 2, 64);
  if (q == 0) y[b * 512 + o] = lrelu_(r + bias[o]);
}

// ---- MLP out: 512 -> 2 ----
__global__ void k_mlp4(const float* __restrict__ f3, const float* __restrict__ Wo,
                       const float* __restrict__ bo, float* __restrict__ out){
  int tid = threadIdx.x;
  int g = tid >> 5, lane = tid & 31;
  int b = g >> 1, o = g & 1;
  const float4* xr = (const float4*)(f3 + b * 512);
  const float4* wr = (const float4*)(Wo + o * 512);
  float4 a = make_float4(0.f, 0.f, 0.f, 0.f);
  #pragma unroll
  for (int mI = 0; mI < 4; mI++){
    int k4 = lane + mI * 32;
    float4 xv = xr[k4], wv = wr[k4];
    a.x = fmaf(xv.x, wv.x, a.x);
    a.y = fmaf(xv.y, wv.y, a.y);
    a.z = fmaf(xv.z, wv.z, a.z);
    a.w = fmaf(xv.w, wv.w, a.w);
  }
  float r = a.x + a.y + a.z + a.w;
  for (int off = 16; off; off >>= 1) r += __shfl_xor(r, off, 64);
  if (lane == 0) out[b * 2 + o] = r + bo[o];
}

extern "C" void kernel_launch(void* const* d_in, const int* in_sizes, int n_in,
                              void* d_out, int out_size, void* d_ws, size_t ws_size,
                              hipStream_t stream) {
  const float* drug  = (const float*)d_in[0];
  const int*   natoms= (const int*)d_in[1];
  const int*   prot  = (const int*)d_in[2];
  const float* emb   = (const float*)d_in[3];
  const float* w1    = (const float*)d_in[4];
  const float* b1    = (const float*)d_in[5];
  const float* w2    = (const float*)d_in[6];
  const float* b2    = (const float*)d_in[7];
  const float* w3    = (const float*)d_in[8];
  const float* b3    = (const float*)d_in[9];
  const float* Wd    = (const float*)d_in[10];
  const float* bd    = (const float*)d_in[11];
  const float* Wp    = (const float*)d_in[12];
  const float* bp    = (const float*)d_in[13];
  const float* Watt  = (const float*)d_in[14];
  const float* batt  = (const float*)d_in[15];
  const float* W1    = (const float*)d_in[16];
  const float* bf1   = (const float*)d_in[17];
  const float* W2    = (const float*)d_in[18];
  const float* bf2   = (const float*)d_in[19];
  const float* W3    = (const float*)d_in[20];
  const float* bf3   = (const float*)d_in[21];
  const float* Wo    = (const float*)d_in[22];
  const float* bo    = (const float*)d_in[23];
  float* out = (float*)d_out;

  float* ws = (float*)d_ws;
  // region layout (floats); h1 region is reused for cmeanT + f1/f2/f3 later
  float* h1     = ws;                       // 160000  (4*40*1000)
  float* cmeanT = ws;                       // 97280   (4*160*152) — after h1 dead
  float* f1     = ws + 97280;               // 4096
  float* f2     = ws + 101376;              // 4096
  float* f3     = ws + 105472;              // 2048
  float* h2     = ws + 160000;              // 317440  (4*80*992)
  float* pconv  = ws + 477440;              // 627200  (4*160*980)
  float* dattT  = ws + 1104640;             // 97280   (4*160*152)
  float* pattT  = ws + 1201920;             // 629760  (4*160*984)
  float* pmeanT = ws + 1831680;             // 629760  (4*160*984)
  unsigned* enc = (unsigned*)(ws + 2461440);// 1280 u32 (denc @0, penc @640)
  float* projG  = ws + 2461760;             // 4186

  k_proj <<<17, 256, 0, stream>>>(emb, w1, projG);
  k_conv1<<<BB * 80, 256, 0, stream>>>(prot, projG, b1, h1);
  k_conv2<<<BB * NC2, 256, 0, stream>>>(h1, w2, b2, h2);
  k_conv3<<<BB * NC3, 256, 0, stream>>>(h2, w3, b3, pconv);
  k_dpatt<<<400, 256, 0, stream>>>(drug, natoms, prot, pconv, Wd, bd, Wp, bp,
                                   dattT, pattT, enc);
  k_means<<<BB * NC3, 256, 0, stream>>>(dattT, pattT, cmeanT, pmeanT);
  k_atte <<<400, 256, 0, stream>>>(cmeanT, pmeanT, Watt, batt, drug, pconv, enc);
  k_mlp1 <<<64, 256, 0, stream>>>(enc, W1, bf1, f1);
  k_mlp2 <<<64, 256, 0, stream>>>(f1, W2, bf2, f2);
  k_mlp3 <<<32, 256, 0, stream>>>(f2, W3, bf3, f3);
  k_mlp4 <<<1, 256, 0, stream>>>(f3, Wo, bo, out);
}